// Round 1
// baseline (352.355 us; speedup 1.0000x reference)
//
#include <hip/hip_runtime.h>

#define BDIM 16384
#define IN_D 151
#define HID_D 200
#define CENT_D 2000

// padded dims (multiples of 64 for K, 128 for N)
#define INP 192     // 151 -> 192 (K of GEMM0)
#define HIDP 256    // 200 -> 256 (N of GEMM0, K of GEMM1)
#define CENTP 2048  // 2000 -> 2048 (N of GEMM1/2, K of GEMM2/3)
#define KERNR 256   // 151/200 -> 256 padded rows for kern/centres (N of GEMM3/0)

using bf16x8 = __attribute__((ext_vector_type(8))) short;
using f32x4  = __attribute__((ext_vector_type(4))) float;

__device__ __forceinline__ unsigned short f2bf(float f) {
  unsigned u = __builtin_bit_cast(unsigned, f);
  u += 0x7FFFu + ((u >> 16) & 1u);   // round-to-nearest-even
  return (unsigned short)(u >> 16);
}
__device__ __forceinline__ float bf2f(unsigned short h) {
  unsigned u = ((unsigned)h) << 16;
  return __builtin_bit_cast(float, u);
}

typedef __attribute__((address_space(1))) const unsigned int guint;
typedef __attribute__((address_space(3))) unsigned int luint;
__device__ __forceinline__ void g2l16(const void* g, void* l) {
  __builtin_amdgcn_global_load_lds((guint*)g, (luint*)l, 16, 0, 0);
}

struct GArgs {
  const unsigned short* A;   // M x K bf16 row-major
  const unsigned short* B;   // N x K bf16 row-major (i.e. B^T layout)
  int K;
  const float* x2; const float* c2; const float* sg2;  // MODE 0
  const float* bias;                                    // MODE 1,2
  unsigned short* obf; int ldo;                         // MODE 0,1,2
  float* of;                                            // MODE 3
};

// C[i][j] = sum_k A[i,k]*B[j,k];  128x128 tile, BK=64, 4 waves (2x2), 16x16x32 MFMA.
// LDS XOR-swizzle (T2) with pre-swizzled global source columns (rule #21 involution).
template<int MODE>
__global__ __launch_bounds__(256) void gemm_bt(GArgs p) {
  __shared__ __align__(16) short As[128 * 64];
  __shared__ __align__(16) short Bs[128 * 64];
  const int tid  = threadIdx.x;
  const int lane = tid & 63;
  const int w    = tid >> 6;
  const int wr   = w >> 1, wc = w & 1;
  const int lr   = lane & 15;
  const int tm = blockIdx.x, tn = blockIdx.y;
  const int K = p.K;
  f32x4 acc[4][4] = {};

  const unsigned short* Ag = p.A + (size_t)tm * 128 * K;
  const unsigned short* Bg = p.B + (size_t)tn * 128 * K;

  int rowc[4], colc[4], ldsc[4];
#pragma unroll
  for (int i = 0; i < 4; i++) {
    int cc = i * 256 + tid;          // 16B-chunk id within the 128x64 tile
    rowc[i] = cc >> 3;               // 8 chunks per 64-element row
    colc[i] = ((cc & 7) ^ (rowc[i] & 7)) * 8;  // pre-swizzled source column
    ldsc[i] = cc * 8;                // linear LDS dest (shorts)
  }

  for (int k0 = 0; k0 < K; k0 += 64) {
    __syncthreads();
#pragma unroll
    for (int i = 0; i < 4; i++)
      g2l16(Ag + (size_t)rowc[i] * K + k0 + colc[i], &As[ldsc[i]]);
#pragma unroll
    for (int i = 0; i < 4; i++)
      g2l16(Bg + (size_t)rowc[i] * K + k0 + colc[i], &Bs[ldsc[i]]);
    __syncthreads();
#pragma unroll
    for (int ks = 0; ks < 2; ks++) {
      bf16x8 af[4], bfr[4];
#pragma unroll
      for (int m = 0; m < 4; m++) {
        int r = wr * 64 + m * 16 + lr;
        af[m] = *(const bf16x8*)&As[r * 64 + ((((ks << 2) + (lane >> 4)) ^ (r & 7)) << 3)];
      }
#pragma unroll
      for (int n = 0; n < 4; n++) {
        int r = wc * 64 + n * 16 + lr;
        bfr[n] = *(const bf16x8*)&Bs[r * 64 + ((((ks << 2) + (lane >> 4)) ^ (r & 7)) << 3)];
      }
#pragma unroll
      for (int m = 0; m < 4; m++)
#pragma unroll
        for (int n = 0; n < 4; n++)
          acc[m][n] = __builtin_amdgcn_mfma_f32_16x16x32_bf16(af[m], bfr[n], acc[m][n], 0, 0, 0);
    }
  }

  // epilogue: C/D layout col=lane&15, row=(lane>>4)*4+reg  [m89-verified]
  const int rb = tm * 128 + wr * 64 + (lane >> 4) * 4;
  const int cb = tn * 128 + wc * 64 + lr;
#pragma unroll
  for (int m = 0; m < 4; m++) {
#pragma unroll
    for (int n = 0; n < 4; n++) {
#pragma unroll
      for (int r = 0; r < 4; r++) {
        const int gi = rb + m * 16 + r;
        const int gj = cb + n * 16;
        const float v = acc[m][n][r];
        if constexpr (MODE == 0) {          // phi = exp(-max(x2+c2-2*dot,0)*sig^2)
          float ph = 0.f;
          if (gj < HID_D) {
            float d2 = fmaxf(p.x2[gi] + p.c2[gj] - 2.f * v, 0.f);
            ph = __expf(-d2 * p.sg2[gj]);
          }
          p.obf[(size_t)gi * p.ldo + gj] = f2bf(ph);
        } else if constexpr (MODE == 1) {   // h = relu(v + b1)
          float b = (gj < CENT_D) ? p.bias[gj] : 0.f;
          p.obf[(size_t)gi * p.ldo + gj] = f2bf(fmaxf(v + b, 0.f));
        } else if constexpr (MODE == 2) {   // out = exp(v + b2), pad cols forced to 0
          float o = (gj < CENT_D) ? __expf(v + p.bias[gj]) : 0.f;
          p.obf[(size_t)gi * p.ldo + gj] = f2bf(o);
        } else {                            // MODE 3: Ehat
          if (gj < IN_D) p.of[(size_t)gi * IN_D + gj] = v;
        }
      }
    }
  }
}

__global__ void cast_pad(const float* __restrict__ src, unsigned short* __restrict__ dst,
                         int R, int C, int Rp, int Cp) {
  int n = Rp * Cp;
  for (int i = blockIdx.x * blockDim.x + threadIdx.x; i < n; i += gridDim.x * blockDim.x) {
    int r = i / Cp, c = i - r * Cp;
    float v = (r < R && c < C) ? src[(size_t)r * C + c] : 0.f;
    dst[i] = f2bf(v);
  }
}

__global__ void rownorm(const float* __restrict__ src, float* __restrict__ dst,
                        int R, int C, int Rp) {
  int row = (int)((blockIdx.x * blockDim.x + threadIdx.x) >> 6);
  int l = threadIdx.x & 63;
  if (row >= Rp) return;
  float s = 0.f;
  if (row < R)
    for (int k = l; k < C; k += 64) { float v = src[(size_t)row * C + k]; s += v * v; }
#pragma unroll
  for (int off = 32; off > 0; off >>= 1) s += __shfl_down(s, off);
  if (l == 0) dst[row] = s;
}

__global__ void sigsq(const float* __restrict__ sg, float* __restrict__ out) {
  int j = threadIdx.x;  // 256 threads, one block
  out[j] = (j < HID_D) ? sg[j] * sg[j] : 0.f;
}

// d_out float layout: [Ehat2 B*151][Rhat B*2000][Ehat2 B*151][Rhat B*2000][x B*151]
__global__ void finalize(float* __restrict__ dout, const unsigned short* __restrict__ outp,
                         const float* __restrict__ x) {
  const int i = blockIdx.x;
  float* Eh = dout;                                   // holds raw Ehat, scaled in place
  float* Ra = dout + (size_t)BDIM * IN_D;
  float* Eb = dout + (size_t)BDIM * (IN_D + CENT_D);
  float* Rb = dout + (size_t)BDIM * (2 * IN_D + CENT_D);
  float* xo = dout + (size_t)BDIM * (2 * IN_D + 2 * CENT_D);
  const float e0 = Eh[(size_t)i * IN_D];
  __syncthreads();   // everyone reads e0 before thread 0 overwrites Eh[i][0]
  const float s = 1.f / e0;
  const int t = threadIdx.x;
  for (int j = t; j < IN_D; j += 256) {
    float v = Eh[(size_t)i * IN_D + j] * s;
    Eh[(size_t)i * IN_D + j] = v;
    Eb[(size_t)i * IN_D + j] = v;
    xo[(size_t)i * IN_D + j] = x[(size_t)i * IN_D + j];
  }
  for (int j = t; j < CENT_D; j += 256) {
    float rv = bf2f(outp[(size_t)i * CENTP + j]) * s;
    Ra[(size_t)i * CENT_D + j] = rv;
    Rb[(size_t)i * CENT_D + j] = rv;
  }
}

extern "C" void kernel_launch(void* const* d_in, const int* in_sizes, int n_in,
                              void* d_out, int out_size, void* d_ws, size_t ws_size,
                              hipStream_t stream) {
  (void)in_sizes; (void)n_in; (void)out_size; (void)ws_size;
  const float* x       = (const float*)d_in[0];
  const float* centres = (const float*)d_in[1];
  const float* sigmas  = (const float*)d_in[2];
  const float* w1      = (const float*)d_in[3];
  const float* b1      = (const float*)d_in[4];
  const float* w2      = (const float*)d_in[5];
  const float* b2      = (const float*)d_in[6];
  const float* kern    = (const float*)d_in[7];
  float* dout = (float*)d_out;

  char* ws = (char*)d_ws;
  size_t off = 0;
  auto alloc = [&](size_t bytes) {
    char* p = ws + off;
    off = (off + bytes + 255) & ~(size_t)255;
    return p;
  };
  unsigned short* x_bf  = (unsigned short*)alloc((size_t)BDIM * INP * 2);
  unsigned short* c_bf  = (unsigned short*)alloc((size_t)KERNR * INP * 2);
  unsigned short* w1p   = (unsigned short*)alloc((size_t)CENTP * HIDP * 2);
  unsigned short* w2p   = (unsigned short*)alloc((size_t)CENTP * CENTP * 2);
  unsigned short* kernp = (unsigned short*)alloc((size_t)KERNR * CENTP * 2);
  unsigned short* phip  = (unsigned short*)alloc((size_t)BDIM * HIDP * 2);
  unsigned short* outp  = (unsigned short*)alloc((size_t)BDIM * CENTP * 2);
  float* x2  = (float*)alloc((size_t)BDIM * 4);
  float* c2  = (float*)alloc((size_t)KERNR * 4);
  float* sg2 = (float*)alloc((size_t)KERNR * 4);
  // h (bf16, B x 2048) lives in the Rhat_b output slot (B*2000 f32 = 131MB >= 67MB);
  // consumed by GEMM2, overwritten by finalize at the end.
  unsigned short* hp = (unsigned short*)(dout + (size_t)BDIM * (2 * IN_D + CENT_D));

  auto cgrid = [](long long n) { long long g = (n + 255) / 256; return (int)(g > 4096 ? 4096 : g); };
  cast_pad<<<cgrid((long long)BDIM * INP), 256, 0, stream>>>(x, x_bf, BDIM, IN_D, BDIM, INP);
  cast_pad<<<cgrid((long long)KERNR * INP), 256, 0, stream>>>(centres, c_bf, HID_D, IN_D, KERNR, INP);
  cast_pad<<<cgrid((long long)CENTP * HIDP), 256, 0, stream>>>(w1, w1p, CENT_D, HID_D, CENTP, HIDP);
  cast_pad<<<cgrid((long long)CENTP * CENTP), 256, 0, stream>>>(w2, w2p, CENT_D, CENT_D, CENTP, CENTP);
  cast_pad<<<cgrid((long long)KERNR * CENTP), 256, 0, stream>>>(kern, kernp, IN_D, CENT_D, KERNR, CENTP);
  rownorm<<<BDIM / 4, 256, 0, stream>>>(x, x2, BDIM, IN_D, BDIM);
  rownorm<<<KERNR / 4, 256, 0, stream>>>(centres, c2, HID_D, IN_D, KERNR);
  sigsq<<<1, 256, 0, stream>>>(sigmas, sg2);

  GArgs g0{}; g0.A = x_bf; g0.B = c_bf; g0.K = INP;
  g0.x2 = x2; g0.c2 = c2; g0.sg2 = sg2; g0.obf = phip; g0.ldo = HIDP;
  gemm_bt<0><<<dim3(BDIM / 128, HIDP / 128), 256, 0, stream>>>(g0);

  GArgs g1{}; g1.A = phip; g1.B = w1p; g1.K = HIDP;
  g1.bias = b1; g1.obf = hp; g1.ldo = CENTP;
  gemm_bt<1><<<dim3(BDIM / 128, CENTP / 128), 256, 0, stream>>>(g1);

  GArgs g2{}; g2.A = hp; g2.B = w2p; g2.K = CENTP;
  g2.bias = b2; g2.obf = outp; g2.ldo = CENTP;
  gemm_bt<2><<<dim3(BDIM / 128, CENTP / 128), 256, 0, stream>>>(g2);

  GArgs g3{}; g3.A = outp; g3.B = kernp; g3.K = CENTP;
  g3.of = dout;  // Ehat -> Ehat2_a slot, rescaled in finalize
  gemm_bt<3><<<dim3(BDIM / 128, KERNR / 128), 256, 0, stream>>>(g3);

  finalize<<<BDIM, 256, 0, stream>>>(dout, outp, x);
}